// Round 16
// baseline (903.890 us; speedup 1.0000x reference)
//
#include <hip/hip_runtime.h>
#include <hip/hip_bf16.h>
#include <math.h>

#define BS   8
#define NP   4096
#define NC   1024
#define KN   32
#define CIN  128
#define CMID 183
#define COUT 256
#define BN_EPS 1e-5f

// ---- workspace layout (bytes) ----
#define OFF_SQ   0                    // BS*NP floats            = 131072
#define OFF_FPS  131072               // BS*NC ints              = 32768
#define OFF_GRP  163840               // BS*NC*KN ints           = 1048576 -> ends 1212416
#define OFF_A1   1212416              // 192 floats (pad 1K)
#define OFF_B1   1213440
#define OFF_A2   1214464              // 256 floats
#define OFF_B2   1215488
#define OFF_W1F  1216512              // 30720 u16 = 61440 B  (B-frag packed, 192x160)
#define OFF_W2F  1277952              // 49152 u16 = 98304 B  (B-frag packed, 256x192)
// total 1376256 bytes

typedef float  f32x4 __attribute__((ext_vector_type(4)));
typedef short  s16x8 __attribute__((ext_vector_type(8)));
typedef unsigned short u16;
typedef u16    u16x8 __attribute__((ext_vector_type(8)));
typedef unsigned long long u64;
typedef unsigned int u32;

static __device__ __forceinline__ u16 f2bf(float f) {
  __hip_bfloat16 h = __float2bfloat16(f);   // RNE
  return __builtin_bit_cast(u16, h);
}

static __device__ __forceinline__ u64 kmax(u64 a, u64 b) { return a > b ? a : b; }
static __device__ __forceinline__ u64 kmin(u64 a, u64 b) { return a < b ? a : b; }

template <int CTRL>
static __device__ __forceinline__ u32 dpp_u32(u32 v) {
  return (u32)__builtin_amdgcn_update_dpp((int)v, (int)v, CTRL, 0xF, 0xF, false);
}

// ============================================================ prep
__global__ __launch_bounds__(256) void prep_kernel(
    const float* __restrict__ xyz,
    const float* __restrict__ W1, const float* __restrict__ W2,
    const float* __restrict__ b1, const float* __restrict__ g1, const float* __restrict__ be1,
    const float* __restrict__ m1, const float* __restrict__ v1,
    const float* __restrict__ b2, const float* __restrict__ g2, const float* __restrict__ be2,
    const float* __restrict__ m2, const float* __restrict__ v2,
    float* __restrict__ sq, float* __restrict__ A1, float* __restrict__ B1,
    float* __restrict__ A2, float* __restrict__ B2,
    u16* __restrict__ W1f, u16* __restrict__ W2f) {
  int i = blockIdx.x * 256 + threadIdx.x;
  if (i < BS * NP) {
    #pragma clang fp contract(off)
    float x = xyz[i*3+0], y = xyz[i*3+1], z = xyz[i*3+2];
    sq[i] = (x*x + y*y) + z*z;
  }
  if (i < 192) {
    float a = 0.f, bb = 0.f;
    if (i < CMID) { a = g1[i] / sqrtf(v1[i] + BN_EPS); bb = fmaf(b1[i] - m1[i], a, be1[i]); }
    A1[i] = a; B1[i] = bb;
  }
  if (i < COUT) { float a = g2[i] / sqrtf(v2[i] + BN_EPS); A2[i] = a; B2[i] = fmaf(b2[i] - m2[i], a, be2[i]); }
  if (i < 30720) {               // W1f: 12 N-tiles x 5 K-tiles
    int j = i & 7, lane = (i >> 3) & 63, r = i >> 9;
    int kt = r % 5, nt = r / 5;
    int n = nt*16 + (lane & 15);
    int k = kt*32 + ((lane >> 4) << 3) + j;
    W1f[i] = (n < CMID && k < 131) ? f2bf(W1[n*131 + k]) : (u16)0;
  }
  if (i < 49152) {               // W2f: 16 N-tiles x 6 K-tiles
    int j = i & 7, lane = (i >> 3) & 63, r = i >> 9;
    int kt = r % 6, nt = r / 6;
    int n = nt*16 + (lane & 15);
    int k = kt*32 + ((lane >> 4) << 3) + j;
    W2f[i] = (k < CMID) ? f2bf(W2[n*CMID + k]) : (u16)0;
  }
}

// ============================================================ FPS (R13/R15, proven 657us — frozen)
#define FPS_T 512

__global__ __launch_bounds__(FPS_T) void fps_kernel(
    const float* __restrict__ xyz,
    int* __restrict__ fps_idx, float* __restrict__ center_out) {
  #pragma clang fp contract(off)
  int b = blockIdx.x, t = threadIdx.x;
  const float* p = xyz + (size_t)b * NP * 3;
  __shared__ float s_xyz[NP * 3];                // 48 KB
  __shared__ u32 s_far[NC];                      // 4 KB
  __shared__ __align__(16) u64 s_part[2][8];     // 128 B
  for (int i = t; i < NP * 3; i += FPS_T) s_xyz[i] = p[i];
  __syncthreads();
  const int PPT = NP / FPS_T;             // 8 points/thread
  int base = t * PPT;
  float px[PPT], py[PPT], pz[PPT], dist[PPT];
  u32 nkey[PPT];
  #pragma unroll
  for (int j = 0; j < PPT; ++j) {
    px[j] = s_xyz[(base+j)*3+0]; py[j] = s_xyz[(base+j)*3+1]; pz[j] = s_xyz[(base+j)*3+2];
    dist[j] = INFINITY;
    nkey[j] = ~(u32)(base + j);
  }
  int lane = t & 63, w = t >> 6;
  u32 far = 0;
  float cx = s_xyz[0], cy = s_xyz[1], cz = s_xyz[2];
  for (int it = 0; it < NC; ++it) {
    if (t == 0) s_far[it] = far;           // LDS only — no vmcnt at the barrier
    // ---- scalar update (exact order: (dx*dx + dy*dy) + dz*dz, no fma) + unique keys
    u64 k[PPT];
    #pragma unroll
    for (int j = 0; j < PPT; ++j) {
      float dx = px[j] - cx, dy = py[j] - cy, dz = pz[j] - cz;
      float d = (dx*dx + dy*dy) + dz*dz;
      float nd = fminf(dist[j], d);
      dist[j] = nd;
      k[j] = ((u64)__builtin_bit_cast(u32, nd) << 32) | nkey[j];
    }
    // ---- local tree argmax (keys unique -> well-defined)
    u64 a0 = kmax(k[0], k[1]), a1 = kmax(k[2], k[3]);
    u64 a2 = kmax(k[4], k[5]), a3 = kmax(k[6], k[7]);
    u64 cur = kmax(kmax(a0, a1), kmax(a2, a3));
    // ---- all-DPP wave reduce: xor1, xor2, ror4, ror8, bcast15, bcast31
    #define DPP_STAGE64(CTRL) {                                          \
      u32 hi_ = (u32)(cur >> 32), lo_ = (u32)cur;                        \
      u32 ohi = dpp_u32<CTRL>(hi_), olo = dpp_u32<CTRL>(lo_);            \
      cur = kmax(cur, ((u64)ohi << 32) | olo);                           \
    }
    DPP_STAGE64(0xB1)    // quad_perm [1,0,3,2]  (xor 1)
    DPP_STAGE64(0x4E)    // quad_perm [2,3,0,1]  (xor 2)
    DPP_STAGE64(0x124)   // row_ror:4
    DPP_STAGE64(0x128)   // row_ror:8  -> each 16-row holds row max
    DPP_STAGE64(0x142)   // row_bcast15 -> lanes16-31 rows0-1 max, 48-63 rows2-3 max
    DPP_STAGE64(0x143)   // row_bcast31 -> lanes48-63 full wave max
    #undef DPP_STAGE64
    int par = it & 1;
    if (lane == 63) s_part[par][w] = cur;
    __syncthreads();
    // ---- combine 8 wave partials (broadcast reads, 3-level tree)
    u64 q0 = kmax(s_part[par][0], s_part[par][1]);
    u64 q1 = kmax(s_part[par][2], s_part[par][3]);
    u64 q2 = kmax(s_part[par][4], s_part[par][5]);
    u64 q3 = kmax(s_part[par][6], s_part[par][7]);
    u64 best = kmax(kmax(q0, q1), kmax(q2, q3));
    far = ~(u32)best;
    cx = s_xyz[far*3+0]; cy = s_xyz[far*3+1]; cz = s_xyz[far*3+2];  // broadcast reads
  }
  // ---- cooperative write-out (once): gather centers from s_xyz via s_far
  __syncthreads();
  for (int i = t; i < NC; i += FPS_T) {
    u32 fi = s_far[i];
    center_out[(size_t)(b*NC + i)*3 + 0] = s_xyz[fi*3+0];
    center_out[(size_t)(b*NC + i)*3 + 1] = s_xyz[fi*3+1];
    center_out[(size_t)(b*NC + i)*3 + 2] = s_xyz[fi*3+2];
    fps_idx[b*NC + i] = (int)fi;
  }
}

// ============================================================ kNN v4 — register-resident distances
// = R11 (proven) with dist array moved LDS -> registers. Nothing ever reads
//   another thread's chunk, so s_d was pure overhead: the per-round winner-
//   owner rescan was a single-lane serial chain of 16 LDS loads (~250cy)
//   stalling every round's barrier; now it is 16 register compares (~90cy)
//   with branchless invalidation (compile-time indices — no scratch).
//   Also deletes the 16-write staging pass and its barrier. Distance values,
//   op order, tie rules, DPP network: identical to R11.
__global__ __launch_bounds__(256) void knn_kernel(
    const float* __restrict__ xyz, const float* __restrict__ sq,
    const int* __restrict__ fps_idx, int* __restrict__ grp) {
  #pragma clang fp contract(off)
  int L = blockIdx.x;
  int b = L & 7, ci = L >> 3;
  int t = threadIdx.x;
  const float* p   = xyz + (size_t)b * NP * 3;
  const float* sqb = sq + b * NP;
  __shared__ __align__(16) u64 s_pk[2][4];
  int center = fps_idx[b*NC + ci];
  float cx = p[center*3+0], cy = p[center*3+1], cz = p[center*3+2];
  float sqi = sqb[center];
  const int PPT = NP / 256;                // 16, strided: thread t owns {t, t+256, ...}
  float dreg[PPT];
  #pragma unroll
  for (int k = 0; k < PPT; ++k) {
    int j = t + k * 256;
    float dot = (cx*p[j*3+0] + cy*p[j*3+1]) + cz*p[j*3+2];   // L->R, no fma
    dreg[k] = (sqi - 2.0f*dot) + sqb[j];
  }
  // local min over register chunk; ascending k => lowest idx on ties
  float lv = INFINITY; int li = 0x7fffffff;
  #pragma unroll
  for (int k = 0; k < PPT; ++k) {
    float v = dreg[k];
    bool bt = v < lv;
    lv = bt ? v : lv; li = bt ? (t + k * 256) : li;
  }
  int lane = t & 63, wave = t >> 6;
  int myidx = 0;
  for (int it = 0; it < KN; ++it) {
    // monotonic float->u32 map (handles negative d): order(bits) == order(float)
    u32 bits = __builtin_bit_cast(u32, lv);
    u32 mb = ((int)bits < 0) ? ~bits : (bits | 0x80000000u);
    u64 cur = ((u64)mb << 32) | (u32)li;
    // all-DPP wave kmin reduce (network proven R10/R11)
    #define DPP_STAGE64N(CTRL) {                                         \
      u32 hi_ = (u32)(cur >> 32), lo_ = (u32)cur;                        \
      u32 ohi = dpp_u32<CTRL>(hi_), olo = dpp_u32<CTRL>(lo_);            \
      cur = kmin(cur, ((u64)ohi << 32) | olo);                           \
    }
    DPP_STAGE64N(0xB1)
    DPP_STAGE64N(0x4E)
    DPP_STAGE64N(0x124)
    DPP_STAGE64N(0x128)
    DPP_STAGE64N(0x142)
    DPP_STAGE64N(0x143)
    #undef DPP_STAGE64N
    int par = it & 1;
    if (lane == 63) s_pk[par][wave] = cur;
    __syncthreads();
    u64 best = kmin(kmin(s_pk[par][0], s_pk[par][1]),
                    kmin(s_pk[par][2], s_pk[par][3]));
    int bi = (int)(u32)best;
    if (t == it) myidx = bi;                 // thread `it` records winner
    if ((bi & 255) == t) {                   // owner invalidates + rescans in REGISTERS
      int kidx = bi >> 8;                    // j = t + k*256 -> k = bi>>8
      #pragma unroll
      for (int k = 0; k < PPT; ++k)
        dreg[k] = (k == kidx) ? INFINITY : dreg[k];   // branchless, static indices
      lv = INFINITY; li = 0x7fffffff;
      #pragma unroll
      for (int k = 0; k < PPT; ++k) {
        float v = dreg[k];
        bool bt = v < lv;
        lv = bt ? v : lv; li = bt ? (t + k * 256) : li;
      }
    }
  }
  if (t < KN) grp[((size_t)(b*NC + ci))*KN + t] = myidx;
}

// ============================================================ fused MLP + maxpool (MFMA bf16, frozen)
__global__ __launch_bounds__(256) void mlp_kernel(
    const float* __restrict__ xyz, const float* __restrict__ fea,
    const u16* __restrict__ W1f, const u16* __restrict__ W2f,
    const float* __restrict__ A1, const float* __restrict__ B1,
    const float* __restrict__ A2, const float* __restrict__ B2,
    const int* __restrict__ grp, const float* __restrict__ center_xyz,
    float* __restrict__ new_fea) {
  int L = blockIdx.x;
  int b = L & 7, pi = L >> 3;
  size_t gbase = (size_t)b * NC + pi * 2;
  int t = threadIdx.x;
  int lane = t & 63, w = t >> 6;

  __shared__ u16 sx[64][168];
  __shared__ u16 sy1[64][200];
  __shared__ int s_gidx[64];
  __shared__ float s_c[2][3];

  if (t < 64) s_gidx[t] = grp[(gbase + (t >> 5)) * KN + (t & 31)];
  if (t < 6)  s_c[t/3][t%3] = center_xyz[(gbase + t/3)*3 + (t%3)];
  __syncthreads();

  {
    int r = t >> 2, q0 = (t & 3) * 32;
    const float* src = fea + ((size_t)b*NP + s_gidx[r])*CIN + q0;
    #pragma unroll
    for (int j = 0; j < 32; j += 8) {
      float4 v0 = *(const float4*)(src + j);
      float4 v1 = *(const float4*)(src + j + 4);
      u16x8 pk;
      pk[0]=f2bf(v0.x); pk[1]=f2bf(v0.y); pk[2]=f2bf(v0.z); pk[3]=f2bf(v0.w);
      pk[4]=f2bf(v1.x); pk[5]=f2bf(v1.y); pk[6]=f2bf(v1.z); pk[7]=f2bf(v1.w);
      *(u16x8*)&sx[r][q0 + j] = pk;
    }
  }
  if (t < 64) {
    int c = t >> 5;
    const float* g = xyz + ((size_t)b*NP + s_gidx[t])*3;
    sx[t][128] = f2bf(g[0] - s_c[c][0]);
    sx[t][129] = f2bf(g[1] - s_c[c][1]);
    sx[t][130] = f2bf(g[2] - s_c[c][2]);
    #pragma unroll
    for (int j = 131; j < 160; ++j) sx[t][j] = 0;
  }
  __syncthreads();

  const f32x4 zero = {0.f, 0.f, 0.f, 0.f};

  // ---- layer 1
  {
    f32x4 acc[4][3];
    #pragma unroll
    for (int mt = 0; mt < 4; ++mt)
      #pragma unroll
      for (int nt = 0; nt < 3; ++nt) acc[mt][nt] = zero;
    #pragma unroll
    for (int kt = 0; kt < 5; ++kt) {
      s16x8 a[4];
      #pragma unroll
      for (int mt = 0; mt < 4; ++mt)
        a[mt] = *(const s16x8*)&sx[mt*16 + (lane & 15)][kt*32 + ((lane >> 4) << 3)];
      s16x8 bf[3];
      #pragma unroll
      for (int nt = 0; nt < 3; ++nt)
        bf[nt] = *(const s16x8*)&W1f[(((w*3 + nt)*5 + kt)*64 + lane) * 8];
      #pragma unroll
      for (int mt = 0; mt < 4; ++mt)
        #pragma unroll
        for (int nt = 0; nt < 3; ++nt)
          acc[mt][nt] = __builtin_amdgcn_mfma_f32_16x16x32_bf16(a[mt], bf[nt], acc[mt][nt], 0, 0, 0);
    }
    #pragma unroll
    for (int nt = 0; nt < 3; ++nt) {
      int c = w*48 + nt*16 + (lane & 15);
      float av = A1[c], bv = B1[c];
      #pragma unroll
      for (int mt = 0; mt < 4; ++mt) {
        #pragma unroll
        for (int r = 0; r < 4; ++r) {
          float v = fmaxf(fmaf(acc[mt][nt][r], av, bv), 0.f);
          sy1[mt*16 + ((lane >> 4) << 2) + r][c] = f2bf(v);
        }
      }
    }
  }
  __syncthreads();

  // ---- layer 2 + BN/ReLU + maxpool
  {
    f32x4 acc[4][4];
    #pragma unroll
    for (int mt = 0; mt < 4; ++mt)
      #pragma unroll
      for (int nt = 0; nt < 4; ++nt) acc[mt][nt] = zero;
    #pragma unroll
    for (int kt = 0; kt < 6; ++kt) {
      s16x8 a[4];
      #pragma unroll
      for (int mt = 0; mt < 4; ++mt)
        a[mt] = *(const s16x8*)&sy1[mt*16 + (lane & 15)][kt*32 + ((lane >> 4) << 3)];
      s16x8 bf[4];
      #pragma unroll
      for (int nt = 0; nt < 4; ++nt)
        bf[nt] = *(const s16x8*)&W2f[(((w*4 + nt)*6 + kt)*64 + lane) * 8];
      #pragma unroll
      for (int mt = 0; mt < 4; ++mt)
        #pragma unroll
        for (int nt = 0; nt < 4; ++nt)
          acc[mt][nt] = __builtin_amdgcn_mfma_f32_16x16x32_bf16(a[mt], bf[nt], acc[mt][nt], 0, 0, 0);
    }
    #pragma unroll
    for (int nt = 0; nt < 4; ++nt) {
      int c = w*64 + nt*16 + (lane & 15);
      float av = A2[c], bv = B2[c];
      float c0 = 0.f, c1 = 0.f;
      #pragma unroll
      for (int mt = 0; mt < 2; ++mt)
        #pragma unroll
        for (int r = 0; r < 4; ++r)
          c0 = fmaxf(c0, fmaf(acc[mt][nt][r], av, bv));
      #pragma unroll
      for (int mt = 2; mt < 4; ++mt)
        #pragma unroll
        for (int r = 0; r < 4; ++r)
          c1 = fmaxf(c1, fmaf(acc[mt][nt][r], av, bv));
      c0 = fmaxf(c0, __shfl_xor(c0, 16)); c0 = fmaxf(c0, __shfl_xor(c0, 32));
      c1 = fmaxf(c1, __shfl_xor(c1, 16)); c1 = fmaxf(c1, __shfl_xor(c1, 32));
      if (lane < 16)      new_fea[gbase*COUT + c] = c0;
      else if (lane < 32) new_fea[(gbase + 1)*COUT + c] = c1;
    }
  }
}

// ============================================================ launch
extern "C" void kernel_launch(void* const* d_in, const int* in_sizes, int n_in,
                              void* d_out, int out_size, void* d_ws, size_t ws_size,
                              hipStream_t stream) {
  const float* xyz = (const float*)d_in[0];
  const float* fea = (const float*)d_in[1];
  const float* W1  = (const float*)d_in[2];
  const float* b1  = (const float*)d_in[3];
  const float* g1  = (const float*)d_in[4];
  const float* be1 = (const float*)d_in[5];
  const float* m1  = (const float*)d_in[6];
  const float* v1  = (const float*)d_in[7];
  const float* W2  = (const float*)d_in[8];
  const float* b2  = (const float*)d_in[9];
  const float* g2  = (const float*)d_in[10];
  const float* be2 = (const float*)d_in[11];
  const float* m2  = (const float*)d_in[12];
  const float* v2  = (const float*)d_in[13];

  char* ws = (char*)d_ws;
  float* sq   = (float*)(ws + OFF_SQ);
  int*   fpsi = (int*)  (ws + OFF_FPS);
  int*   grp  = (int*)  (ws + OFF_GRP);
  float* A1   = (float*)(ws + OFF_A1);
  float* B1   = (float*)(ws + OFF_B1);
  float* A2   = (float*)(ws + OFF_A2);
  float* B2   = (float*)(ws + OFF_B2);
  u16*   W1f  = (u16*)  (ws + OFF_W1F);
  u16*   W2f  = (u16*)  (ws + OFF_W2F);

  float* out        = (float*)d_out;
  float* center_out = out;                   // [BS][NC][3]
  float* new_fea    = out + (size_t)BS*NC*3; // [BS][NC][COUT]

  prep_kernel<<<192, 256, 0, stream>>>(xyz, W1, W2, b1,g1,be1,m1,v1, b2,g2,be2,m2,v2,
                                       sq, A1,B1,A2,B2, W1f, W2f);
  fps_kernel<<<BS, FPS_T, 0, stream>>>(xyz, fpsi, center_out);
  knn_kernel<<<BS*NC, 256, 0, stream>>>(xyz, sq, fpsi, grp);
  mlp_kernel<<<BS*NC/2, 256, 0, stream>>>(xyz, fea, W1f, W2f, A1,B1,A2,B2,
                                          grp, center_out, new_fea);
}

// Round 17
// 838.464 us; speedup vs baseline: 1.0780x; 1.0780x over previous
//
#include <hip/hip_runtime.h>
#include <hip/hip_bf16.h>
#include <math.h>

#define BS   8
#define NP   4096
#define NC   1024
#define KN   32
#define CIN  128
#define CMID 183
#define COUT 256
#define BN_EPS 1e-5f

// ---- workspace layout (bytes) ----
#define OFF_SQ   0                    // BS*NP floats            = 131072
#define OFF_FPS  131072               // BS*NC ints              = 32768
#define OFF_GRP  163840               // BS*NC*KN ints           = 1048576 -> ends 1212416
#define OFF_A1   1212416              // 192 floats (pad 1K)
#define OFF_B1   1213440
#define OFF_A2   1214464              // 256 floats
#define OFF_B2   1215488
#define OFF_W1F  1216512              // 30720 u16 = 61440 B  (B-frag packed, 192x160)
#define OFF_W2F  1277952              // 49152 u16 = 98304 B  (B-frag packed, 256x192)
// total 1376256 bytes

typedef float  f32x4 __attribute__((ext_vector_type(4)));
typedef short  s16x8 __attribute__((ext_vector_type(8)));
typedef unsigned short u16;
typedef u16    u16x8 __attribute__((ext_vector_type(8)));
typedef unsigned long long u64;
typedef unsigned int u32;

static __device__ __forceinline__ u16 f2bf(float f) {
  __hip_bfloat16 h = __float2bfloat16(f);   // RNE
  return __builtin_bit_cast(u16, h);
}

static __device__ __forceinline__ u64 kmax(u64 a, u64 b) { return a > b ? a : b; }
static __device__ __forceinline__ u64 kmin(u64 a, u64 b) { return a < b ? a : b; }

template <int CTRL>
static __device__ __forceinline__ u32 dpp_u32(u32 v) {
  return (u32)__builtin_amdgcn_update_dpp((int)v, (int)v, CTRL, 0xF, 0xF, false);
}

// ============================================================ prep
__global__ __launch_bounds__(256) void prep_kernel(
    const float* __restrict__ xyz,
    const float* __restrict__ W1, const float* __restrict__ W2,
    const float* __restrict__ b1, const float* __restrict__ g1, const float* __restrict__ be1,
    const float* __restrict__ m1, const float* __restrict__ v1,
    const float* __restrict__ b2, const float* __restrict__ g2, const float* __restrict__ be2,
    const float* __restrict__ m2, const float* __restrict__ v2,
    float* __restrict__ sq, float* __restrict__ A1, float* __restrict__ B1,
    float* __restrict__ A2, float* __restrict__ B2,
    u16* __restrict__ W1f, u16* __restrict__ W2f) {
  int i = blockIdx.x * 256 + threadIdx.x;
  if (i < BS * NP) {
    #pragma clang fp contract(off)
    float x = xyz[i*3+0], y = xyz[i*3+1], z = xyz[i*3+2];
    sq[i] = (x*x + y*y) + z*z;
  }
  if (i < 192) {
    float a = 0.f, bb = 0.f;
    if (i < CMID) { a = g1[i] / sqrtf(v1[i] + BN_EPS); bb = fmaf(b1[i] - m1[i], a, be1[i]); }
    A1[i] = a; B1[i] = bb;
  }
  if (i < COUT) { float a = g2[i] / sqrtf(v2[i] + BN_EPS); A2[i] = a; B2[i] = fmaf(b2[i] - m2[i], a, be2[i]); }
  if (i < 30720) {               // W1f: 12 N-tiles x 5 K-tiles
    int j = i & 7, lane = (i >> 3) & 63, r = i >> 9;
    int kt = r % 5, nt = r / 5;
    int n = nt*16 + (lane & 15);
    int k = kt*32 + ((lane >> 4) << 3) + j;
    W1f[i] = (n < CMID && k < 131) ? f2bf(W1[n*131 + k]) : (u16)0;
  }
  if (i < 49152) {               // W2f: 16 N-tiles x 6 K-tiles
    int j = i & 7, lane = (i >> 3) & 63, r = i >> 9;
    int kt = r % 6, nt = r / 6;
    int n = nt*16 + (lane & 15);
    int k = kt*32 + ((lane >> 4) << 3) + j;
    W2f[i] = (k < CMID) ? f2bf(W2[n*CMID + k]) : (u16)0;
  }
}

// ============================================================ FPS (R13/R15, proven 657us — frozen)
#define FPS_T 512

__global__ __launch_bounds__(FPS_T) void fps_kernel(
    const float* __restrict__ xyz,
    int* __restrict__ fps_idx, float* __restrict__ center_out) {
  #pragma clang fp contract(off)
  int b = blockIdx.x, t = threadIdx.x;
  const float* p = xyz + (size_t)b * NP * 3;
  __shared__ float s_xyz[NP * 3];                // 48 KB
  __shared__ u32 s_far[NC];                      // 4 KB
  __shared__ __align__(16) u64 s_part[2][8];     // 128 B
  for (int i = t; i < NP * 3; i += FPS_T) s_xyz[i] = p[i];
  __syncthreads();
  const int PPT = NP / FPS_T;             // 8 points/thread
  int base = t * PPT;
  float px[PPT], py[PPT], pz[PPT], dist[PPT];
  u32 nkey[PPT];
  #pragma unroll
  for (int j = 0; j < PPT; ++j) {
    px[j] = s_xyz[(base+j)*3+0]; py[j] = s_xyz[(base+j)*3+1]; pz[j] = s_xyz[(base+j)*3+2];
    dist[j] = INFINITY;
    nkey[j] = ~(u32)(base + j);
  }
  int lane = t & 63, w = t >> 6;
  u32 far = 0;
  float cx = s_xyz[0], cy = s_xyz[1], cz = s_xyz[2];
  for (int it = 0; it < NC; ++it) {
    if (t == 0) s_far[it] = far;           // LDS only — no vmcnt at the barrier
    // ---- scalar update (exact order: (dx*dx + dy*dy) + dz*dz, no fma) + unique keys
    u64 k[PPT];
    #pragma unroll
    for (int j = 0; j < PPT; ++j) {
      float dx = px[j] - cx, dy = py[j] - cy, dz = pz[j] - cz;
      float d = (dx*dx + dy*dy) + dz*dz;
      float nd = fminf(dist[j], d);
      dist[j] = nd;
      k[j] = ((u64)__builtin_bit_cast(u32, nd) << 32) | nkey[j];
    }
    // ---- local tree argmax (keys unique -> well-defined)
    u64 a0 = kmax(k[0], k[1]), a1 = kmax(k[2], k[3]);
    u64 a2 = kmax(k[4], k[5]), a3 = kmax(k[6], k[7]);
    u64 cur = kmax(kmax(a0, a1), kmax(a2, a3));
    // ---- all-DPP wave reduce: xor1, xor2, ror4, ror8, bcast15, bcast31
    #define DPP_STAGE64(CTRL) {                                          \
      u32 hi_ = (u32)(cur >> 32), lo_ = (u32)cur;                        \
      u32 ohi = dpp_u32<CTRL>(hi_), olo = dpp_u32<CTRL>(lo_);            \
      cur = kmax(cur, ((u64)ohi << 32) | olo);                           \
    }
    DPP_STAGE64(0xB1)    // quad_perm [1,0,3,2]  (xor 1)
    DPP_STAGE64(0x4E)    // quad_perm [2,3,0,1]  (xor 2)
    DPP_STAGE64(0x124)   // row_ror:4
    DPP_STAGE64(0x128)   // row_ror:8  -> each 16-row holds row max
    DPP_STAGE64(0x142)   // row_bcast15 -> lanes16-31 rows0-1 max, 48-63 rows2-3 max
    DPP_STAGE64(0x143)   // row_bcast31 -> lanes48-63 full wave max
    #undef DPP_STAGE64
    int par = it & 1;
    if (lane == 63) s_part[par][w] = cur;
    __syncthreads();
    // ---- combine 8 wave partials (broadcast reads, 3-level tree)
    u64 q0 = kmax(s_part[par][0], s_part[par][1]);
    u64 q1 = kmax(s_part[par][2], s_part[par][3]);
    u64 q2 = kmax(s_part[par][4], s_part[par][5]);
    u64 q3 = kmax(s_part[par][6], s_part[par][7]);
    u64 best = kmax(kmax(q0, q1), kmax(q2, q3));
    far = ~(u32)best;
    cx = s_xyz[far*3+0]; cy = s_xyz[far*3+1]; cz = s_xyz[far*3+2];  // broadcast reads
  }
  // ---- cooperative write-out (once): gather centers from s_xyz via s_far
  __syncthreads();
  for (int i = t; i < NC; i += FPS_T) {
    u32 fi = s_far[i];
    center_out[(size_t)(b*NC + i)*3 + 0] = s_xyz[fi*3+0];
    center_out[(size_t)(b*NC + i)*3 + 1] = s_xyz[fi*3+1];
    center_out[(size_t)(b*NC + i)*3 + 2] = s_xyz[fi*3+2];
    fps_idx[b*NC + i] = (int)fi;
  }
}

// ============================================================ kNN (R11, proven — frozen)
__global__ __launch_bounds__(256) void knn_kernel(
    const float* __restrict__ xyz, const float* __restrict__ sq,
    const int* __restrict__ fps_idx, int* __restrict__ grp) {
  #pragma clang fp contract(off)
  int L = blockIdx.x;
  int b = L & 7, ci = L >> 3;
  int t = threadIdx.x;
  const float* p   = xyz + (size_t)b * NP * 3;
  const float* sqb = sq + b * NP;
  __shared__ float s_d[NP];
  __shared__ __align__(16) u64 s_pk[2][4];
  int center = fps_idx[b*NC + ci];
  float cx = p[center*3+0], cy = p[center*3+1], cz = p[center*3+2];
  float sqi = sqb[center];
  const int PPT = NP / 256;                // 16, strided
  #pragma unroll
  for (int k = 0; k < PPT; ++k) {
    int j = t + k * 256;
    float dot = (cx*p[j*3+0] + cy*p[j*3+1]) + cz*p[j*3+2];   // L->R, no fma
    s_d[j] = (sqi - 2.0f*dot) + sqb[j];
  }
  __syncthreads();
  // local min over strided chunk (conflict-free); ascending k => lowest idx on ties
  float lv = INFINITY; int li = 0x7fffffff;
  #pragma unroll
  for (int k = 0; k < PPT; ++k) {
    float v = s_d[t + k * 256];
    bool bt = v < lv;
    lv = bt ? v : lv; li = bt ? (t + k * 256) : li;
  }
  int lane = t & 63, wave = t >> 6;
  int myidx = 0;
  for (int it = 0; it < KN; ++it) {
    // monotonic float->u32 map (handles negative d): order(bits) == order(float)
    u32 bits = __builtin_bit_cast(u32, lv);
    u32 mb = ((int)bits < 0) ? ~bits : (bits | 0x80000000u);
    u64 cur = ((u64)mb << 32) | (u32)li;
    // all-DPP wave kmin reduce (network proven in FPS R10)
    #define DPP_STAGE64N(CTRL) {                                         \
      u32 hi_ = (u32)(cur >> 32), lo_ = (u32)cur;                        \
      u32 ohi = dpp_u32<CTRL>(hi_), olo = dpp_u32<CTRL>(lo_);            \
      cur = kmin(cur, ((u64)ohi << 32) | olo);                           \
    }
    DPP_STAGE64N(0xB1)
    DPP_STAGE64N(0x4E)
    DPP_STAGE64N(0x124)
    DPP_STAGE64N(0x128)
    DPP_STAGE64N(0x142)
    DPP_STAGE64N(0x143)
    #undef DPP_STAGE64N
    int par = it & 1;
    if (lane == 63) s_pk[par][wave] = cur;
    __syncthreads();
    u64 best = kmin(kmin(s_pk[par][0], s_pk[par][1]),
                    kmin(s_pk[par][2], s_pk[par][3]));
    int bi = (int)(u32)best;
    if (t == it) myidx = bi;                 // thread `it` records winner
    if ((bi & 255) == t) {                   // owner invalidates + rescans (strided)
      s_d[bi] = INFINITY;
      lv = INFINITY; li = 0x7fffffff;
      #pragma unroll
      for (int k = 0; k < PPT; ++k) {
        float v = s_d[t + k * 256];
        bool bt = v < lv;
        lv = bt ? v : lv; li = bt ? (t + k * 256) : li;
      }
    }
  }
  if (t < KN) grp[((size_t)(b*NC + ci))*KN + t] = myidx;
}

// ============================================================ fused MLP + maxpool (MFMA bf16, frozen)
__global__ __launch_bounds__(256) void mlp_kernel(
    const float* __restrict__ xyz, const float* __restrict__ fea,
    const u16* __restrict__ W1f, const u16* __restrict__ W2f,
    const float* __restrict__ A1, const float* __restrict__ B1,
    const float* __restrict__ A2, const float* __restrict__ B2,
    const int* __restrict__ grp, const float* __restrict__ center_xyz,
    float* __restrict__ new_fea) {
  int L = blockIdx.x;
  int b = L & 7, pi = L >> 3;
  size_t gbase = (size_t)b * NC + pi * 2;
  int t = threadIdx.x;
  int lane = t & 63, w = t >> 6;

  __shared__ u16 sx[64][168];
  __shared__ u16 sy1[64][200];
  __shared__ int s_gidx[64];
  __shared__ float s_c[2][3];

  if (t < 64) s_gidx[t] = grp[(gbase + (t >> 5)) * KN + (t & 31)];
  if (t < 6)  s_c[t/3][t%3] = center_xyz[(gbase + t/3)*3 + (t%3)];
  __syncthreads();

  {
    int r = t >> 2, q0 = (t & 3) * 32;
    const float* src = fea + ((size_t)b*NP + s_gidx[r])*CIN + q0;
    #pragma unroll
    for (int j = 0; j < 32; j += 8) {
      float4 v0 = *(const float4*)(src + j);
      float4 v1 = *(const float4*)(src + j + 4);
      u16x8 pk;
      pk[0]=f2bf(v0.x); pk[1]=f2bf(v0.y); pk[2]=f2bf(v0.z); pk[3]=f2bf(v0.w);
      pk[4]=f2bf(v1.x); pk[5]=f2bf(v1.y); pk[6]=f2bf(v1.z); pk[7]=f2bf(v1.w);
      *(u16x8*)&sx[r][q0 + j] = pk;
    }
  }
  if (t < 64) {
    int c = t >> 5;
    const float* g = xyz + ((size_t)b*NP + s_gidx[t])*3;
    sx[t][128] = f2bf(g[0] - s_c[c][0]);
    sx[t][129] = f2bf(g[1] - s_c[c][1]);
    sx[t][130] = f2bf(g[2] - s_c[c][2]);
    #pragma unroll
    for (int j = 131; j < 160; ++j) sx[t][j] = 0;
  }
  __syncthreads();

  const f32x4 zero = {0.f, 0.f, 0.f, 0.f};

  // ---- layer 1
  {
    f32x4 acc[4][3];
    #pragma unroll
    for (int mt = 0; mt < 4; ++mt)
      #pragma unroll
      for (int nt = 0; nt < 3; ++nt) acc[mt][nt] = zero;
    #pragma unroll
    for (int kt = 0; kt < 5; ++kt) {
      s16x8 a[4];
      #pragma unroll
      for (int mt = 0; mt < 4; ++mt)
        a[mt] = *(const s16x8*)&sx[mt*16 + (lane & 15)][kt*32 + ((lane >> 4) << 3)];
      s16x8 bf[3];
      #pragma unroll
      for (int nt = 0; nt < 3; ++nt)
        bf[nt] = *(const s16x8*)&W1f[(((w*3 + nt)*5 + kt)*64 + lane) * 8];
      #pragma unroll
      for (int mt = 0; mt < 4; ++mt)
        #pragma unroll
        for (int nt = 0; nt < 3; ++nt)
          acc[mt][nt] = __builtin_amdgcn_mfma_f32_16x16x32_bf16(a[mt], bf[nt], acc[mt][nt], 0, 0, 0);
    }
    #pragma unroll
    for (int nt = 0; nt < 3; ++nt) {
      int c = w*48 + nt*16 + (lane & 15);
      float av = A1[c], bv = B1[c];
      #pragma unroll
      for (int mt = 0; mt < 4; ++mt) {
        #pragma unroll
        for (int r = 0; r < 4; ++r) {
          float v = fmaxf(fmaf(acc[mt][nt][r], av, bv), 0.f);
          sy1[mt*16 + ((lane >> 4) << 2) + r][c] = f2bf(v);
        }
      }
    }
  }
  __syncthreads();

  // ---- layer 2 + BN/ReLU + maxpool
  {
    f32x4 acc[4][4];
    #pragma unroll
    for (int mt = 0; mt < 4; ++mt)
      #pragma unroll
      for (int nt = 0; nt < 4; ++nt) acc[mt][nt] = zero;
    #pragma unroll
    for (int kt = 0; kt < 6; ++kt) {
      s16x8 a[4];
      #pragma unroll
      for (int mt = 0; mt < 4; ++mt)
        a[mt] = *(const s16x8*)&sy1[mt*16 + (lane & 15)][kt*32 + ((lane >> 4) << 3)];
      s16x8 bf[4];
      #pragma unroll
      for (int nt = 0; nt < 4; ++nt)
        bf[nt] = *(const s16x8*)&W2f[(((w*4 + nt)*6 + kt)*64 + lane) * 8];
      #pragma unroll
      for (int mt = 0; mt < 4; ++mt)
        #pragma unroll
        for (int nt = 0; nt < 4; ++nt)
          acc[mt][nt] = __builtin_amdgcn_mfma_f32_16x16x32_bf16(a[mt], bf[nt], acc[mt][nt], 0, 0, 0);
    }
    #pragma unroll
    for (int nt = 0; nt < 4; ++nt) {
      int c = w*64 + nt*16 + (lane & 15);
      float av = A2[c], bv = B2[c];
      float c0 = 0.f, c1 = 0.f;
      #pragma unroll
      for (int mt = 0; mt < 2; ++mt)
        #pragma unroll
        for (int r = 0; r < 4; ++r)
          c0 = fmaxf(c0, fmaf(acc[mt][nt][r], av, bv));
      #pragma unroll
      for (int mt = 2; mt < 4; ++mt)
        #pragma unroll
        for (int r = 0; r < 4; ++r)
          c1 = fmaxf(c1, fmaf(acc[mt][nt][r], av, bv));
      c0 = fmaxf(c0, __shfl_xor(c0, 16)); c0 = fmaxf(c0, __shfl_xor(c0, 32));
      c1 = fmaxf(c1, __shfl_xor(c1, 16)); c1 = fmaxf(c1, __shfl_xor(c1, 32));
      if (lane < 16)      new_fea[gbase*COUT + c] = c0;
      else if (lane < 32) new_fea[(gbase + 1)*COUT + c] = c1;
    }
  }
}

// ============================================================ launch
extern "C" void kernel_launch(void* const* d_in, const int* in_sizes, int n_in,
                              void* d_out, int out_size, void* d_ws, size_t ws_size,
                              hipStream_t stream) {
  const float* xyz = (const float*)d_in[0];
  const float* fea = (const float*)d_in[1];
  const float* W1  = (const float*)d_in[2];
  const float* b1  = (const float*)d_in[3];
  const float* g1  = (const float*)d_in[4];
  const float* be1 = (const float*)d_in[5];
  const float* m1  = (const float*)d_in[6];
  const float* v1  = (const float*)d_in[7];
  const float* W2  = (const float*)d_in[8];
  const float* b2  = (const float*)d_in[9];
  const float* g2  = (const float*)d_in[10];
  const float* be2 = (const float*)d_in[11];
  const float* m2  = (const float*)d_in[12];
  const float* v2  = (const float*)d_in[13];

  char* ws = (char*)d_ws;
  float* sq   = (float*)(ws + OFF_SQ);
  int*   fpsi = (int*)  (ws + OFF_FPS);
  int*   grp  = (int*)  (ws + OFF_GRP);
  float* A1   = (float*)(ws + OFF_A1);
  float* B1   = (float*)(ws + OFF_B1);
  float* A2   = (float*)(ws + OFF_A2);
  float* B2   = (float*)(ws + OFF_B2);
  u16*   W1f  = (u16*)  (ws + OFF_W1F);
  u16*   W2f  = (u16*)  (ws + OFF_W2F);

  float* out        = (float*)d_out;
  float* center_out = out;                   // [BS][NC][3]
  float* new_fea    = out + (size_t)BS*NC*3; // [BS][NC][COUT]

  prep_kernel<<<192, 256, 0, stream>>>(xyz, W1, W2, b1,g1,be1,m1,v1, b2,g2,be2,m2,v2,
                                       sq, A1,B1,A2,B2, W1f, W2f);
  fps_kernel<<<BS, FPS_T, 0, stream>>>(xyz, fpsi, center_out);
  knn_kernel<<<BS*NC, 256, 0, stream>>>(xyz, sq, fpsi, grp);
  mlp_kernel<<<BS*NC/2, 256, 0, stream>>>(xyz, fea, W1f, W2f, A1,B1,A2,B2,
                                          grp, center_out, new_fea);
}